// Round 5
// baseline (647.390 us; speedup 1.0000x reference)
//
#include <hip/hip_runtime.h>
#include <hip/hip_bf16.h>
#include <hip/hip_fp8.h>

// ---------------------------------------------------------------------------
// NanoGPT block on MI355X (gfx950). Round 5:
//  1) LDS-repacked coalesced epilogue stores (dwordx4) for all bf16 tiles
//  2) P and V in OCP fp8 e4m3; PV GEMM uses mfma_f32_16x16x32_fp8_fp8
// Lsum stays exact (fp32 sums of pre-quantization exp values).
// ---------------------------------------------------------------------------

#define DDIM 768
#define TT   4096
#define NB   4
#define ROWS (NB * TT)   // 16384
#define CTS  136         // ctile row stride (bf16 elems): bank-spread + 16B align

using bf16 = __hip_bfloat16;
typedef __bf16 bf16x8 __attribute__((ext_vector_type(8)));
typedef float  f32x4  __attribute__((ext_vector_type(4)));

__device__ __forceinline__ float to_f(float x) { return x; }
__device__ __forceinline__ float to_f(bf16 x) { return __bfloat162float(x); }

__device__ __forceinline__ unsigned char to_fp8(float f) {
  __hip_fp8_e4m3 t(f);
  return (unsigned char)t.__x;
}

// Async global->LDS, 16B per lane. LDS dest is wave-uniform base + lane*16.
__device__ __forceinline__ void gload16(const void* g, void* l) {
#if __has_builtin(__builtin_amdgcn_global_load_lds)
  __builtin_amdgcn_global_load_lds(
      (const __attribute__((address_space(1))) void*)g,
      (__attribute__((address_space(3))) void*)l, 16, 0, 0);
#else
  int lane = threadIdx.x & 63;
  ((int4*)l)[lane] = *(const int4*)g;
#endif
}

// ---------------------------------------------------------------------------
// bf16 GEMM: C[M x N] = A[M x K] * B[N x K]^T, 128x128 tile, 4 waves.
// MODE 3: +bias, ReLU, store bf16 (repacked coalesced)
// MODE 4: +bias, +resid, store fp32 (scalar stores)
// MODE 5: store fp8 exp(v*scale), accumulate row sums into Lsum; XCD swizzle
// ---------------------------------------------------------------------------
template <int MODE, int NT, int MT>
__global__ __launch_bounds__(256) void gemm_bt(
    const bf16* __restrict__ A, int lda, long sA,
    const bf16* __restrict__ B, int ldb, long sB,
    void* __restrict__ Cout, int ldc, long sC, int K, float scale,
    const float* __restrict__ bias, const float* __restrict__ resid,
    float* __restrict__ Lsum) {
  constexpr int SMEMN = (MODE == 4) ? 8192 : (128 * CTS);
  __shared__ __align__(16) bf16 smem[SMEMN];
  __shared__ float Lred[128];
  bf16* As = smem;
  bf16* Bs = smem + 4096;

  int bx, by, bz;
  if constexpr (NT > 0) {
    const int h   = blockIdx.x;
    const int xcd = h & 7;
    const int s   = h >> 3;
    bx = s % NT;
    const int group = (s / NT) * 8 + xcd;
    by = group % MT;
    bz = group / MT;
  } else {
    bx = blockIdx.x; by = blockIdx.y; bz = blockIdx.z;
  }

  A += (long)bz * sA;
  B += (long)bz * sB;

  const int tid  = threadIdx.x;
  const int wave = tid >> 6;
  const int lane = tid & 63;
  const int l16  = lane & 15;
  const int lq   = lane >> 4;
  const int wm   = wave >> 1;
  const int wn   = wave & 1;
  const long tileM = (long)by * 128;
  const long tileN = (long)bx * 128;

  if constexpr (MODE == 5) {
    if (tid < 128) Lred[tid] = 0.f;
  }

  f32x4 acc[4][4] = {};

  const int c0 = wave * 128 + lane;
  const int c1 = c0 + 64;
  bf16* ldsA0 = &As[(wave * 128 + 0) * 8];
  bf16* ldsA1 = &As[(wave * 128 + 64) * 8];
  bf16* ldsB0 = &Bs[(wave * 128 + 0) * 8];
  bf16* ldsB1 = &Bs[(wave * 128 + 64) * 8];
  const long ar0 = (tileM + (c0 >> 2)) * (long)lda + (c0 & 3) * 8;
  const long ar1 = (tileM + (c1 >> 2)) * (long)lda + (c1 & 3) * 8;
  const long br0 = (tileN + (c0 >> 2)) * (long)ldb + (c0 & 3) * 8;
  const long br1 = (tileN + (c1 >> 2)) * (long)ldb + (c1 & 3) * 8;

  for (int k0 = 0; k0 < K; k0 += 32) {
    gload16(A + ar0 + k0, ldsA0);
    gload16(A + ar1 + k0, ldsA1);
    gload16(B + br0 + k0, ldsB0);
    gload16(B + br1 + k0, ldsB1);
    __syncthreads();

    bf16x8 af[4], bf_[4];
#pragma unroll
    for (int i = 0; i < 4; ++i)
      af[i] = *(const bf16x8*)&As[(wm * 64 + i * 16 + l16) * 32 + lq * 8];
#pragma unroll
    for (int j = 0; j < 4; ++j)
      bf_[j] = *(const bf16x8*)&Bs[(wn * 64 + j * 16 + l16) * 32 + lq * 8];
#pragma unroll
    for (int i = 0; i < 4; ++i)
#pragma unroll
      for (int j = 0; j < 4; ++j)
        acc[i][j] = __builtin_amdgcn_mfma_f32_16x16x32_bf16(af[i], bf_[j],
                                                            acc[i][j], 0, 0, 0);
    __syncthreads();
  }

  // C/D layout: col = lane&15, row = quad*4 + reg  [m89/m91 verified]
  if constexpr (MODE == 5) {
    bf16* ctile = smem;  // staging dead after last barrier
    float ps[4][4] = {};
#pragma unroll
    for (int i = 0; i < 4; ++i)
#pragma unroll
      for (int j = 0; j < 4; ++j)
#pragma unroll
        for (int r = 0; r < 4; ++r) {
          float p = __expf(acc[i][j][r] * scale);
          ctile[(wm * 64 + i * 16 + lq * 4 + r) * CTS + wn * 64 + j * 16 + l16] =
              __float2bfloat16(p);
          ps[i][r] += p;
        }
#pragma unroll
    for (int i = 0; i < 4; ++i)
#pragma unroll
      for (int r = 0; r < 4; ++r) {
        float v = ps[i][r];
        v += __shfl_xor(v, 1);
        v += __shfl_xor(v, 2);
        v += __shfl_xor(v, 4);
        v += __shfl_xor(v, 8);
        if (l16 == 0) atomicAdd(&Lred[wm * 64 + i * 16 + lq * 4 + r], v);
      }
    __syncthreads();
    if (tid < 128) atomicAdd(&Lsum[(long)bz * TT + tileM + tid], Lred[tid]);
    // coalesced fp8 readout: 8B per lane
    unsigned char* Pz = (unsigned char*)Cout + (long)bz * sC;
#pragma unroll
    for (int p = 0; p < 8; ++p) {
      const int rr = p * 16 + (tid >> 4);
      const int cc = (tid & 15) * 8;
      bf16x8 v = *(bf16x8*)&ctile[rr * CTS + cc];
      union { unsigned char b[8]; uint2 u; } pk;
#pragma unroll
      for (int e = 0; e < 8; ++e) pk.b[e] = to_fp8((float)v[e]);
      *(uint2*)&Pz[(long)(tileM + rr) * ldc + tileN + cc] = pk.u;
    }
  } else if constexpr (MODE == 3) {
    bf16* ctile = smem;
#pragma unroll
    for (int j = 0; j < 4; ++j) {
      const float bj = bias[tileN + wn * 64 + j * 16 + l16];
#pragma unroll
      for (int i = 0; i < 4; ++i)
#pragma unroll
        for (int r = 0; r < 4; ++r) {
          float v = acc[i][j][r] + bj;
          v = v > 0.f ? v : 0.f;
          ctile[(wm * 64 + i * 16 + lq * 4 + r) * CTS + wn * 64 + j * 16 + l16] =
              __float2bfloat16(v);
        }
    }
    __syncthreads();
    bf16* Cb = (bf16*)Cout;
#pragma unroll
    for (int p = 0; p < 8; ++p) {
      const int rr = p * 16 + (tid >> 4);
      const int cc = (tid & 15) * 8;
      float4 v = *(float4*)&ctile[rr * CTS + cc];
      *(float4*)&Cb[(long)(tileM + rr) * ldc + tileN + cc] = v;
    }
  } else {  // MODE 4: fp32 out, scalar stores
#pragma unroll
    for (int i = 0; i < 4; ++i)
#pragma unroll
      for (int j = 0; j < 4; ++j)
#pragma unroll
        for (int r = 0; r < 4; ++r) {
          const long row = tileM + wm * 64 + i * 16 + lq * 4 + r;
          const long col = tileN + wn * 64 + j * 16 + l16;
          float v = acc[i][j][r] + bias[col] + resid[row * ldc + col];
          ((float*)Cout)[row * ldc + col] = v;
        }
  }
}

// ---------------------------------------------------------------------------
// PV GEMM, fp8 x fp8: O[z][128 x 768-tile] = P[z] (fp8) * Vt (fp8)^T / Lsum.
// XCD swizzle NT=6, MT=32. Output bf16, repacked coalesced.
// ---------------------------------------------------------------------------
__global__ __launch_bounds__(256) void gemm_pv(
    const unsigned char* __restrict__ P,   // [NB][TT][TT] fp8 rows
    const unsigned char* __restrict__ Vt,  // [DDIM][ROWS] fp8
    bf16* __restrict__ O,                  // [ROWS][DDIM]
    const float* __restrict__ Lsum) {
  __shared__ __align__(16) unsigned char smem8[128 * CTS * 2];
  unsigned char* As8 = smem8;           // 128 x 32 fp8 = 4 KB
  unsigned char* Bs8 = smem8 + 4096;    // 128 x 32 fp8 = 4 KB
  bf16* ctile = (bf16*)smem8;

  const int h   = blockIdx.x;
  const int xcd = h & 7;
  const int s   = h >> 3;
  const int bx  = s % 6;
  const int grp = (s / 6) * 8 + xcd;
  const int by  = grp % 32;
  const int bz  = grp / 32;

  const int tid  = threadIdx.x;
  const int wave = tid >> 6;
  const int lane = tid & 63;
  const int l16  = lane & 15;
  const int lq   = lane >> 4;
  const int wm   = wave >> 1;
  const int wn   = wave & 1;
  const long tileM = (long)by * 128;
  const long tileN = (long)bx * 128;

  const unsigned char* Pz = P + (long)bz * TT * TT;
  const unsigned char* Vz = Vt + (long)bz * TT;

  f32x4 acc[4][4] = {};

  // staging: chunk c (16B) = tile row c>>1, half c&1; one gload per wave/op
  const int c = wave * 64 + lane;
  const long pa = (tileM + (c >> 1)) * (long)TT + (c & 1) * 16;
  const long va = (tileN + (c >> 1)) * (long)ROWS + (c & 1) * 16;
  unsigned char* ldsA = As8 + wave * 1024;
  unsigned char* ldsB = Bs8 + wave * 1024;

  for (int k0 = 0; k0 < TT; k0 += 32) {
    gload16(Pz + pa + k0, ldsA);
    gload16(Vz + va + k0, ldsB);
    __syncthreads();

    long af[4], bfr[4];
#pragma unroll
    for (int i = 0; i < 4; ++i)
      af[i] = *(const long*)&As8[(wm * 64 + i * 16 + l16) * 32 + lq * 8];
#pragma unroll
    for (int j = 0; j < 4; ++j)
      bfr[j] = *(const long*)&Bs8[(wn * 64 + j * 16 + l16) * 32 + lq * 8];
#pragma unroll
    for (int i = 0; i < 4; ++i)
#pragma unroll
      for (int j = 0; j < 4; ++j)
        acc[i][j] = __builtin_amdgcn_mfma_f32_16x16x32_fp8_fp8(
            af[i], bfr[j], acc[i][j], 0, 0, 0);
    __syncthreads();
  }

  float inv[4][4];
#pragma unroll
  for (int i = 0; i < 4; ++i)
#pragma unroll
    for (int r = 0; r < 4; ++r)
      inv[i][r] =
          1.0f / Lsum[(long)bz * TT + tileM + wm * 64 + i * 16 + lq * 4 + r];
#pragma unroll
  for (int i = 0; i < 4; ++i)
#pragma unroll
    for (int j = 0; j < 4; ++j)
#pragma unroll
      for (int r = 0; r < 4; ++r)
        ctile[(wm * 64 + i * 16 + lq * 4 + r) * CTS + wn * 64 + j * 16 + l16] =
            __float2bfloat16(acc[i][j][r] * inv[i][r]);
  __syncthreads();
#pragma unroll
  for (int p = 0; p < 8; ++p) {
    const int rr = p * 16 + (tid >> 4);
    const int cc = (tid & 15) * 8;
    float4 v = *(float4*)&ctile[rr * CTS + cc];
    *(float4*)&O[((long)bz * TT + tileM + rr) * DDIM + tileN + cc] = v;
  }
}

// ---------------------------------------------------------------------------
// Fused QKV projection: z=0,1 -> bf16 Qm/Km (repacked); z=2 -> fp8 V^T
// (transposed repack). A is y1 (16384 x 768), weights N x K bf16.
// ---------------------------------------------------------------------------
__global__ __launch_bounds__(256) void gemm_qkv(
    const bf16* __restrict__ A,
    const bf16* __restrict__ Wq, const bf16* __restrict__ Wk,
    const bf16* __restrict__ Wv, bf16* __restrict__ Qm,
    bf16* __restrict__ Km, unsigned char* __restrict__ Vt) {
  __shared__ __align__(16) bf16 smem[128 * CTS];
  bf16* As = smem;
  bf16* Bs = smem + 4096;
  bf16* ctile = smem;

  const int z = blockIdx.z;
  const bf16* B = (z == 0) ? Wq : (z == 1) ? Wk : Wv;

  const int tid  = threadIdx.x;
  const int wave = tid >> 6;
  const int lane = tid & 63;
  const int l16  = lane & 15;
  const int lq   = lane >> 4;
  const int wm   = wave >> 1;
  const int wn   = wave & 1;
  const long tileM = (long)blockIdx.y * 128;
  const long tileN = (long)blockIdx.x * 128;

  f32x4 acc[4][4] = {};

  const int c0 = wave * 128 + lane;
  const int c1 = c0 + 64;
  bf16* ldsA0 = &As[(wave * 128 + 0) * 8];
  bf16* ldsA1 = &As[(wave * 128 + 64) * 8];
  bf16* ldsB0 = &Bs[(wave * 128 + 0) * 8];
  bf16* ldsB1 = &Bs[(wave * 128 + 64) * 8];
  const long ar0 = (tileM + (c0 >> 2)) * (long)DDIM + (c0 & 3) * 8;
  const long ar1 = (tileM + (c1 >> 2)) * (long)DDIM + (c1 & 3) * 8;
  const long br0 = (tileN + (c0 >> 2)) * (long)DDIM + (c0 & 3) * 8;
  const long br1 = (tileN + (c1 >> 2)) * (long)DDIM + (c1 & 3) * 8;

  for (int k0 = 0; k0 < DDIM; k0 += 32) {
    gload16(A + ar0 + k0, ldsA0);
    gload16(A + ar1 + k0, ldsA1);
    gload16(B + br0 + k0, ldsB0);
    gload16(B + br1 + k0, ldsB1);
    __syncthreads();

    bf16x8 af[4], bf_[4];
#pragma unroll
    for (int i = 0; i < 4; ++i)
      af[i] = *(const bf16x8*)&As[(wm * 64 + i * 16 + l16) * 32 + lq * 8];
#pragma unroll
    for (int j = 0; j < 4; ++j)
      bf_[j] = *(const bf16x8*)&Bs[(wn * 64 + j * 16 + l16) * 32 + lq * 8];
#pragma unroll
    for (int i = 0; i < 4; ++i)
#pragma unroll
      for (int j = 0; j < 4; ++j)
        acc[i][j] = __builtin_amdgcn_mfma_f32_16x16x32_bf16(af[i], bf_[j],
                                                            acc[i][j], 0, 0, 0);
    __syncthreads();
  }

  if (z < 2) {
#pragma unroll
    for (int i = 0; i < 4; ++i)
#pragma unroll
      for (int j = 0; j < 4; ++j)
#pragma unroll
        for (int r = 0; r < 4; ++r)
          ctile[(wm * 64 + i * 16 + lq * 4 + r) * CTS + wn * 64 + j * 16 + l16] =
              __float2bfloat16(acc[i][j][r]);
    __syncthreads();
    bf16* Cp = (z == 0) ? Qm : Km;
#pragma unroll
    for (int p = 0; p < 8; ++p) {
      const int rr = p * 16 + (tid >> 4);
      const int cc = (tid & 15) * 8;
      float4 v = *(float4*)&ctile[rr * CTS + cc];
      *(float4*)&Cp[(long)(tileM + rr) * DDIM + tileN + cc] = v;
    }
  } else {
    // transposed repack: ctile[n][m], 4 consecutive m per lane -> b64 writes
#pragma unroll
    for (int i = 0; i < 4; ++i)
#pragma unroll
      for (int j = 0; j < 4; ++j) {
        union { bf16 h[4]; uint2 u; } w;
#pragma unroll
        for (int r = 0; r < 4; ++r) w.h[r] = __float2bfloat16(acc[i][j][r]);
        *(uint2*)&ctile[(wn * 64 + j * 16 + l16) * CTS + wm * 64 + i * 16 +
                        lq * 4] = w.u;
      }
    __syncthreads();
#pragma unroll
    for (int p = 0; p < 8; ++p) {
      const int rr = p * 16 + (tid >> 4);   // n index
      const int cc = (tid & 15) * 8;        // m chunk
      bf16x8 v = *(bf16x8*)&ctile[rr * CTS + cc];
      union { unsigned char b[8]; uint2 u; } pk;
#pragma unroll
      for (int e = 0; e < 8; ++e) pk.b[e] = to_fp8((float)v[e]);
      *(uint2*)&Vt[(long)(tileN + rr) * ROWS + tileM + cc] = pk.u;
    }
  }
}

// ---------------------------------------------------------------------------
// LayerNorm (faithful buggy form): y = (x - mu/sqrt(var)) * g + b, ddof=1.
// One 256-thr block per 768-elem row. Optionally zeroes Lzero[row].
// ---------------------------------------------------------------------------
template <typename T>
__global__ __launch_bounds__(256) void ln_kernel(
    const T* __restrict__ in, const float* __restrict__ g,
    const float* __restrict__ beta, bf16* __restrict__ out,
    float* __restrict__ Lzero) {
  const long row = blockIdx.x;
  if (Lzero != nullptr && threadIdx.x == 0) Lzero[row] = 0.f;
  const T* xr = in + row * DDIM;
  const int t = threadIdx.x;
  float v0 = to_f(xr[t]), v1 = to_f(xr[t + 256]), v2 = to_f(xr[t + 512]);
  float s = v0 + v1 + v2;
  float q = v0 * v0 + v1 * v1 + v2 * v2;
#pragma unroll
  for (int o = 32; o; o >>= 1) {
    s += __shfl_down(s, o);
    q += __shfl_down(q, o);
  }
  __shared__ float sb[4], qb[4];
  if ((t & 63) == 0) { sb[t >> 6] = s; qb[t >> 6] = q; }
  __syncthreads();
  const float S = sb[0] + sb[1] + sb[2] + sb[3];
  const float Q = qb[0] + qb[1] + qb[2] + qb[3];
  const float mu  = S * (1.0f / 768.0f);
  const float var = (Q - 768.0f * mu * mu) * (1.0f / 767.0f);
  const float sub = mu / sqrtf(var);
  bf16* orow = out + row * DDIM;
  orow[t]       = __float2bfloat16((v0 - sub) * g[t]       + beta[t]);
  orow[t + 256] = __float2bfloat16((v1 - sub) * g[t + 256] + beta[t + 256]);
  orow[t + 512] = __float2bfloat16((v2 - sub) * g[t + 512] + beta[t + 512]);
}

// ---------------------------------------------------------------------------
// Weight prep: z=0..2 transpose+cast wq/wk/wv; z=3..4 cast fc1/fc2.
// ---------------------------------------------------------------------------
__global__ void prep_weights(const float* __restrict__ wq,
                             const float* __restrict__ wk,
                             const float* __restrict__ wv,
                             const float* __restrict__ f1,
                             const float* __restrict__ f2,
                             bf16* wqt, bf16* wkt, bf16* wvt, bf16* f1b,
                             bf16* f2b) {
  __shared__ float tile[32][33];
  const float* src;
  bf16* dst;
  bool tr = true;
  switch (blockIdx.z) {
    case 0: src = wq; dst = wqt; break;
    case 1: src = wk; dst = wkt; break;
    case 2: src = wv; dst = wvt; break;
    case 3: src = f1; dst = f1b; tr = false; break;
    default: src = f2; dst = f2b; tr = false; break;
  }
  const int tx = threadIdx.x, ty = threadIdx.y;
  const int x = blockIdx.x * 32 + tx;
  const int y = blockIdx.y * 32 + ty;
  if (tr) {
#pragma unroll
    for (int r = 0; r < 4; ++r) tile[ty + 8 * r][tx] = src[(y + 8 * r) * DDIM + x];
    __syncthreads();
    const int ox = blockIdx.y * 32 + tx;
    const int oy = blockIdx.x * 32 + ty;
#pragma unroll
    for (int r = 0; r < 4; ++r)
      dst[(oy + 8 * r) * DDIM + ox] = __float2bfloat16(tile[tx][ty + 8 * r]);
  } else {
#pragma unroll
    for (int r = 0; r < 4; ++r)
      dst[(y + 8 * r) * DDIM + x] = __float2bfloat16(src[(y + 8 * r) * DDIM + x]);
  }
}

// ---------------------------------------------------------------------------
extern "C" void kernel_launch(void* const* d_in, const int* in_sizes, int n_in,
                              void* d_out, int out_size, void* d_ws,
                              size_t ws_size, hipStream_t stream) {
  const float* x     = (const float*)d_in[0];
  const float* ln1_g = (const float*)d_in[1];
  const float* ln1_b = (const float*)d_in[2];
  const float* wq    = (const float*)d_in[3];
  const float* wk    = (const float*)d_in[4];
  const float* wv    = (const float*)d_in[5];
  const float* ln2_g = (const float*)d_in[6];
  const float* ln2_b = (const float*)d_in[7];
  const float* f1w   = (const float*)d_in[8];
  const float* f1bias= (const float*)d_in[9];
  const float* f2w   = (const float*)d_in[10];
  const float* f2bias= (const float*)d_in[11];
  float* out = (float*)d_out;

  char* ws = (char*)d_ws;
  size_t off = 0;
  auto take = [&](size_t bytes) -> char* {
    char* p = ws + off;
    off += (bytes + 255) & ~(size_t)255;
    return p;
  };
  const size_t WB = (size_t)DDIM * DDIM * sizeof(bf16);
  const size_t MB = (size_t)ROWS * DDIM * sizeof(bf16);
  bf16* wqt = (bf16*)take(WB);
  bf16* wkt = (bf16*)take(WB);
  bf16* wvt = (bf16*)take(WB);
  bf16* f1b = (bf16*)take(WB);
  bf16* f2b = (bf16*)take(WB);
  float* Lsum = (float*)take((size_t)ROWS * sizeof(float));
  bf16* y1  = (bf16*)take(MB);
  bf16* Qm  = (bf16*)take(MB);
  bf16* Km  = (bf16*)take(MB);
  unsigned char* Vt8 = (unsigned char*)take((size_t)DDIM * ROWS);  // 12.6 MB
  unsigned char* Sb8 = (unsigned char*)take((size_t)NB * TT * TT); // 67 MB (P)
  // buffer reuse (strictly sequential stream):
  bf16* O  = y1;  // attention output (y1 dead after QKV)
  bf16* y2 = Qm;  // LN2 output      (Q dead after QK^T)
  bf16* h  = Km;  // MLP hidden      (K dead after QK^T)

  prep_weights<<<dim3(24, 24, 5), dim3(32, 8), 0, stream>>>(
      wq, wk, wv, f1w, f2w, wqt, wkt, wvt, f1b, f2b);

  // LN1 also zeroes Lsum (ws is re-poisoned before every timed call)
  ln_kernel<float><<<ROWS, 256, 0, stream>>>(x, ln1_g, ln1_b, y1, Lsum);

  // Fused QKV projections (M=16384, N=768, K=768); z=2 emits fp8 V^T
  gemm_qkv<<<dim3(6, 128, 3), 256, 0, stream>>>(y1, wqt, wkt, wvt, Qm, Km, Vt8);

  const float scale = 0.03608439182435161f;  // 1/sqrt(768)
  // P = exp(scale * Q K^T) -> fp8, + exact fp32 row sums -> Lsum
  gemm_bt<5, 32, 32><<<dim3(32 * 32 * NB), 256, 0, stream>>>(
      Qm, DDIM, (long)TT * DDIM, Km, DDIM, (long)TT * DDIM, Sb8, TT,
      (long)TT * TT, DDIM, scale, nullptr, nullptr, Lsum);

  // O = (P V) / Lsum, fp8 x fp8 MFMA
  gemm_pv<<<dim3(6 * 32 * NB), 256, 0, stream>>>(Sb8, Vt8, O, Lsum);

  ln_kernel<bf16><<<ROWS, 256, 0, stream>>>(O, ln2_g, ln2_b, y2, nullptr);

  // MLP
  gemm_bt<3, 0, 0><<<dim3(6, 128, 1), 256, 0, stream>>>(
      y2, DDIM, 0, f1b, DDIM, 0, h, DDIM, 0, DDIM, 1.f, f1bias, nullptr,
      nullptr);
  gemm_bt<4, 0, 0><<<dim3(6, 128, 1), 256, 0, stream>>>(
      h, DDIM, 0, f2b, DDIM, 0, out, DDIM, 0, DDIM, 1.f, f2bias, x, nullptr);
}

// Round 6
// 646.115 us; speedup vs baseline: 1.0020x; 1.0020x over previous
//
#include <hip/hip_runtime.h>
#include <hip/hip_bf16.h>
#include <hip/hip_fp8.h>

// ---------------------------------------------------------------------------
// NanoGPT block on MI355X (gfx950). Round 6:
//  - QK^T computes S^T (A=K, B=Q) so the MFMA C-layout puts 4 consecutive
//    k-columns of one Q-row in each lane -> hardware cvt_pk_fp8 + single
//    dword store per (i,j). No LDS repack, no software fp8 ctor.
//  - Same packed direct store for fp8 V^T in the QKV kernel.
//  - P stays fp8 e4m3 (halved traffic, round-5 win), PV fp8 MFMA.
// ---------------------------------------------------------------------------

#define DDIM 768
#define TT   4096
#define NB   4
#define ROWS (NB * TT)   // 16384
#define CTS  136         // bf16 ctile row stride (bank-spread + 16B align)

using bf16 = __hip_bfloat16;
typedef __bf16 bf16x8 __attribute__((ext_vector_type(8)));
typedef float  f32x4  __attribute__((ext_vector_type(4)));

__device__ __forceinline__ float to_f(float x) { return x; }
__device__ __forceinline__ float to_f(bf16 x) { return __bfloat162float(x); }

// Pack 4 fp32 -> 4 fp8 e4m3 bytes (hardware cvt on gfx950).
__device__ __forceinline__ int pack_fp8x4(float a, float b, float c, float d) {
#if __has_builtin(__builtin_amdgcn_cvt_pk_fp8_f32)
  int w = __builtin_amdgcn_cvt_pk_fp8_f32(a, b, 0, false);
  w = __builtin_amdgcn_cvt_pk_fp8_f32(c, d, w, true);
  return w;
#else
  union { unsigned char bb[4]; int w; } u;
  u.bb[0] = (unsigned char)__hip_fp8_e4m3(a).__x;
  u.bb[1] = (unsigned char)__hip_fp8_e4m3(b).__x;
  u.bb[2] = (unsigned char)__hip_fp8_e4m3(c).__x;
  u.bb[3] = (unsigned char)__hip_fp8_e4m3(d).__x;
  return u.w;
#endif
}

// Async global->LDS, 16B per lane. LDS dest is wave-uniform base + lane*16.
__device__ __forceinline__ void gload16(const void* g, void* l) {
#if __has_builtin(__builtin_amdgcn_global_load_lds)
  __builtin_amdgcn_global_load_lds(
      (const __attribute__((address_space(1))) void*)g,
      (__attribute__((address_space(3))) void*)l, 16, 0, 0);
#else
  int lane = threadIdx.x & 63;
  ((int4*)l)[lane] = *(const int4*)g;
#endif
}

// ---------------------------------------------------------------------------
// bf16 GEMM: C[M x N] = A[M x K] * B[N x K]^T, 128x128 tile, 4 waves.
// MODE 3: +bias, ReLU, store bf16 (LDS-repacked coalesced)
// MODE 4: +bias, +resid, store fp32 (scalar stores)
// MODE 5: A=K,B=Q -> acc=S^T; store P=exp(v*scale) as packed fp8 dwords
//         directly to global (row-major P[q][k]); row sums -> Lsum.
// ---------------------------------------------------------------------------
template <int MODE, int NT, int MT>
__global__ __launch_bounds__(256) void gemm_bt(
    const bf16* __restrict__ A, int lda, long sA,
    const bf16* __restrict__ B, int ldb, long sB,
    void* __restrict__ Cout, int ldc, long sC, int K, float scale,
    const float* __restrict__ bias, const float* __restrict__ resid,
    float* __restrict__ Lsum) {
  constexpr int SMEMN = (MODE == 3) ? (128 * CTS) : 8192;
  __shared__ __align__(16) bf16 smem[SMEMN];
  __shared__ float Lred[128];
  bf16* As = smem;
  bf16* Bs = smem + 4096;

  int bx, by, bz;
  if constexpr (NT > 0) {
    const int h   = blockIdx.x;
    const int xcd = h & 7;
    const int s   = h >> 3;
    bx = s % NT;
    const int group = (s / NT) * 8 + xcd;
    by = group % MT;
    bz = group / MT;
  } else {
    bx = blockIdx.x; by = blockIdx.y; bz = blockIdx.z;
  }

  A += (long)bz * sA;
  B += (long)bz * sB;

  const int tid  = threadIdx.x;
  const int wave = tid >> 6;
  const int lane = tid & 63;
  const int l16  = lane & 15;
  const int lq   = lane >> 4;
  const int wm   = wave >> 1;
  const int wn   = wave & 1;
  const long tileM = (long)by * 128;
  const long tileN = (long)bx * 128;

  if constexpr (MODE == 5) {
    if (tid < 128) Lred[tid] = 0.f;
  }

  f32x4 acc[4][4] = {};

  const int c0 = wave * 128 + lane;
  const int c1 = c0 + 64;
  bf16* ldsA0 = &As[(wave * 128 + 0) * 8];
  bf16* ldsA1 = &As[(wave * 128 + 64) * 8];
  bf16* ldsB0 = &Bs[(wave * 128 + 0) * 8];
  bf16* ldsB1 = &Bs[(wave * 128 + 64) * 8];
  const long ar0 = (tileM + (c0 >> 2)) * (long)lda + (c0 & 3) * 8;
  const long ar1 = (tileM + (c1 >> 2)) * (long)lda + (c1 & 3) * 8;
  const long br0 = (tileN + (c0 >> 2)) * (long)ldb + (c0 & 3) * 8;
  const long br1 = (tileN + (c1 >> 2)) * (long)ldb + (c1 & 3) * 8;

  for (int k0 = 0; k0 < K; k0 += 32) {
    gload16(A + ar0 + k0, ldsA0);
    gload16(A + ar1 + k0, ldsA1);
    gload16(B + br0 + k0, ldsB0);
    gload16(B + br1 + k0, ldsB1);
    __syncthreads();

    bf16x8 af[4], bf_[4];
#pragma unroll
    for (int i = 0; i < 4; ++i)
      af[i] = *(const bf16x8*)&As[(wm * 64 + i * 16 + l16) * 32 + lq * 8];
#pragma unroll
    for (int j = 0; j < 4; ++j)
      bf_[j] = *(const bf16x8*)&Bs[(wn * 64 + j * 16 + l16) * 32 + lq * 8];
#pragma unroll
    for (int i = 0; i < 4; ++i)
#pragma unroll
      for (int j = 0; j < 4; ++j)
        acc[i][j] = __builtin_amdgcn_mfma_f32_16x16x32_bf16(af[i], bf_[j],
                                                            acc[i][j], 0, 0, 0);
    __syncthreads();
  }

  // C/D layout: col(n) = lane&15, row(m) = quad*4 + reg  [m89/m91 verified]
  if constexpr (MODE == 5) {
    // acc = S^T tile: m-dim = k (K rows), n-dim = q (Q rows).
    // Per lane & (i,j): 4 consecutive k at one q -> packed fp8 dword.
    unsigned char* Pz = (unsigned char*)Cout + (long)bz * sC;
    float ps[4] = {0.f, 0.f, 0.f, 0.f};
#pragma unroll
    for (int j = 0; j < 4; ++j) {
      const long qrow = tileN + wn * 64 + j * 16 + l16;
#pragma unroll
      for (int i = 0; i < 4; ++i) {
        const float p0 = __expf(acc[i][j][0] * scale);
        const float p1 = __expf(acc[i][j][1] * scale);
        const float p2 = __expf(acc[i][j][2] * scale);
        const float p3 = __expf(acc[i][j][3] * scale);
        ps[j] += (p0 + p1) + (p2 + p3);
        const int w = pack_fp8x4(p0, p1, p2, p3);
        const long kcol = tileM + wm * 64 + i * 16 + lq * 4;
        *(int*)&Pz[qrow * (long)ldc + kcol] = w;
      }
    }
    // reduce partial q-row sums over the quad bits (lane bits 4-5)
#pragma unroll
    for (int j = 0; j < 4; ++j) {
      float v = ps[j];
      v += __shfl_xor(v, 16);
      v += __shfl_xor(v, 32);
      if (lq == 0) atomicAdd(&Lred[wn * 64 + j * 16 + l16], v);
    }
    __syncthreads();
    if (tid < 128) atomicAdd(&Lsum[(long)bz * TT + tileN + tid], Lred[tid]);
  } else if constexpr (MODE == 3) {
    bf16* ctile = smem;
#pragma unroll
    for (int j = 0; j < 4; ++j) {
      const float bj = bias[tileN + wn * 64 + j * 16 + l16];
#pragma unroll
      for (int i = 0; i < 4; ++i)
#pragma unroll
        for (int r = 0; r < 4; ++r) {
          float v = acc[i][j][r] + bj;
          v = v > 0.f ? v : 0.f;
          ctile[(wm * 64 + i * 16 + lq * 4 + r) * CTS + wn * 64 + j * 16 + l16] =
              __float2bfloat16(v);
        }
    }
    __syncthreads();
    bf16* Cb = (bf16*)Cout;
#pragma unroll
    for (int p = 0; p < 8; ++p) {
      const int rr = p * 16 + (tid >> 4);
      const int cc = (tid & 15) * 8;
      float4 v = *(float4*)&ctile[rr * CTS + cc];
      *(float4*)&Cb[(long)(tileM + rr) * ldc + tileN + cc] = v;
    }
  } else {  // MODE 4: fp32 out (+bias +resid), scalar stores
#pragma unroll
    for (int i = 0; i < 4; ++i)
#pragma unroll
      for (int j = 0; j < 4; ++j)
#pragma unroll
        for (int r = 0; r < 4; ++r) {
          const long row = tileM + wm * 64 + i * 16 + lq * 4 + r;
          const long col = tileN + wn * 64 + j * 16 + l16;
          float v = acc[i][j][r] + bias[col] + resid[row * ldc + col];
          ((float*)Cout)[row * ldc + col] = v;
        }
  }
}

// ---------------------------------------------------------------------------
// PV GEMM, fp8 x fp8: O[z] = (P[z] * V[z]) / Lsum. XCD swizzle NT=6, MT=32.
// Output bf16, LDS-repacked coalesced.
// ---------------------------------------------------------------------------
__global__ __launch_bounds__(256) void gemm_pv(
    const unsigned char* __restrict__ P,   // [NB][TT][TT] fp8 rows
    const unsigned char* __restrict__ Vt,  // [DDIM][ROWS] fp8
    bf16* __restrict__ O,                  // [ROWS][DDIM]
    const float* __restrict__ Lsum) {
  __shared__ __align__(16) unsigned char smem8[128 * CTS * 2];
  unsigned char* As8 = smem8;           // 128 x 32 fp8 = 4 KB
  unsigned char* Bs8 = smem8 + 4096;    // 128 x 32 fp8 = 4 KB
  bf16* ctile = (bf16*)smem8;

  const int h   = blockIdx.x;
  const int xcd = h & 7;
  const int s   = h >> 3;
  const int bx  = s % 6;
  const int grp = (s / 6) * 8 + xcd;
  const int by  = grp % 32;
  const int bz  = grp / 32;

  const int tid  = threadIdx.x;
  const int wave = tid >> 6;
  const int lane = tid & 63;
  const int l16  = lane & 15;
  const int lq   = lane >> 4;
  const int wm   = wave >> 1;
  const int wn   = wave & 1;
  const long tileM = (long)by * 128;
  const long tileN = (long)bx * 128;

  const unsigned char* Pz = P + (long)bz * TT * TT;
  const unsigned char* Vz = Vt + (long)bz * TT;

  f32x4 acc[4][4] = {};

  const int c = wave * 64 + lane;
  const long pa = (tileM + (c >> 1)) * (long)TT + (c & 1) * 16;
  const long va = (tileN + (c >> 1)) * (long)ROWS + (c & 1) * 16;
  unsigned char* ldsA = As8 + wave * 1024;
  unsigned char* ldsB = Bs8 + wave * 1024;

  for (int k0 = 0; k0 < TT; k0 += 32) {
    gload16(Pz + pa + k0, ldsA);
    gload16(Vz + va + k0, ldsB);
    __syncthreads();

    long af[4], bfr[4];
#pragma unroll
    for (int i = 0; i < 4; ++i)
      af[i] = *(const long*)&As8[(wm * 64 + i * 16 + l16) * 32 + lq * 8];
#pragma unroll
    for (int j = 0; j < 4; ++j)
      bfr[j] = *(const long*)&Bs8[(wn * 64 + j * 16 + l16) * 32 + lq * 8];
#pragma unroll
    for (int i = 0; i < 4; ++i)
#pragma unroll
      for (int j = 0; j < 4; ++j)
        acc[i][j] = __builtin_amdgcn_mfma_f32_16x16x32_fp8_fp8(
            af[i], bfr[j], acc[i][j], 0, 0, 0);
    __syncthreads();
  }

  float inv[4][4];
#pragma unroll
  for (int i = 0; i < 4; ++i)
#pragma unroll
    for (int r = 0; r < 4; ++r)
      inv[i][r] =
          1.0f / Lsum[(long)bz * TT + tileM + wm * 64 + i * 16 + lq * 4 + r];
#pragma unroll
  for (int i = 0; i < 4; ++i)
#pragma unroll
    for (int j = 0; j < 4; ++j)
#pragma unroll
      for (int r = 0; r < 4; ++r)
        ctile[(wm * 64 + i * 16 + lq * 4 + r) * CTS + wn * 64 + j * 16 + l16] =
            __float2bfloat16(acc[i][j][r] * inv[i][r]);
  __syncthreads();
#pragma unroll
  for (int p = 0; p < 8; ++p) {
    const int rr = p * 16 + (tid >> 4);
    const int cc = (tid & 15) * 8;
    float4 v = *(float4*)&ctile[rr * CTS + cc];
    *(float4*)&O[((long)bz * TT + tileM + rr) * DDIM + tileN + cc] = v;
  }
}

// ---------------------------------------------------------------------------
// Fused QKV projection: z=0,1 -> bf16 Qm/Km (LDS-repacked); z=2 -> fp8 V^T
// via packed cvt + direct dword stores (no LDS). A = y1, weights N x K bf16.
// ---------------------------------------------------------------------------
__global__ __launch_bounds__(256) void gemm_qkv(
    const bf16* __restrict__ A,
    const bf16* __restrict__ Wq, const bf16* __restrict__ Wk,
    const bf16* __restrict__ Wv, bf16* __restrict__ Qm,
    bf16* __restrict__ Km, unsigned char* __restrict__ Vt) {
  __shared__ __align__(16) bf16 smem[128 * CTS];
  bf16* As = smem;
  bf16* Bs = smem + 4096;
  bf16* ctile = smem;

  const int z = blockIdx.z;
  const bf16* B = (z == 0) ? Wq : (z == 1) ? Wk : Wv;

  const int tid  = threadIdx.x;
  const int wave = tid >> 6;
  const int lane = tid & 63;
  const int l16  = lane & 15;
  const int lq   = lane >> 4;
  const int wm   = wave >> 1;
  const int wn   = wave & 1;
  const long tileM = (long)blockIdx.y * 128;
  const long tileN = (long)blockIdx.x * 128;

  f32x4 acc[4][4] = {};

  const int c0 = wave * 128 + lane;
  const int c1 = c0 + 64;
  bf16* ldsA0 = &As[(wave * 128 + 0) * 8];
  bf16* ldsA1 = &As[(wave * 128 + 64) * 8];
  bf16* ldsB0 = &Bs[(wave * 128 + 0) * 8];
  bf16* ldsB1 = &Bs[(wave * 128 + 64) * 8];
  const long ar0 = (tileM + (c0 >> 2)) * (long)DDIM + (c0 & 3) * 8;
  const long ar1 = (tileM + (c1 >> 2)) * (long)DDIM + (c1 & 3) * 8;
  const long br0 = (tileN + (c0 >> 2)) * (long)DDIM + (c0 & 3) * 8;
  const long br1 = (tileN + (c1 >> 2)) * (long)DDIM + (c1 & 3) * 8;

  for (int k0 = 0; k0 < DDIM; k0 += 32) {
    gload16(A + ar0 + k0, ldsA0);
    gload16(A + ar1 + k0, ldsA1);
    gload16(B + br0 + k0, ldsB0);
    gload16(B + br1 + k0, ldsB1);
    __syncthreads();

    bf16x8 af[4], bf_[4];
#pragma unroll
    for (int i = 0; i < 4; ++i)
      af[i] = *(const bf16x8*)&As[(wm * 64 + i * 16 + l16) * 32 + lq * 8];
#pragma unroll
    for (int j = 0; j < 4; ++j)
      bf_[j] = *(const bf16x8*)&Bs[(wn * 64 + j * 16 + l16) * 32 + lq * 8];
#pragma unroll
    for (int i = 0; i < 4; ++i)
#pragma unroll
      for (int j = 0; j < 4; ++j)
        acc[i][j] = __builtin_amdgcn_mfma_f32_16x16x32_bf16(af[i], bf_[j],
                                                            acc[i][j], 0, 0, 0);
    __syncthreads();
  }

  if (z < 2) {
#pragma unroll
    for (int i = 0; i < 4; ++i)
#pragma unroll
      for (int j = 0; j < 4; ++j)
#pragma unroll
        for (int r = 0; r < 4; ++r)
          ctile[(wm * 64 + i * 16 + lq * 4 + r) * CTS + wn * 64 + j * 16 + l16] =
              __float2bfloat16(acc[i][j][r]);
    __syncthreads();
    bf16* Cp = (z == 0) ? Qm : Km;
#pragma unroll
    for (int p = 0; p < 8; ++p) {
      const int rr = p * 16 + (tid >> 4);
      const int cc = (tid & 15) * 8;
      float4 v = *(float4*)&ctile[rr * CTS + cc];
      *(float4*)&Cp[(long)(tileM + rr) * DDIM + tileN + cc] = v;
    }
  } else {
    // V^T fp8: row n = tileN + wn*64 + j*16 + l16 (V col), cols m packed 4x.
#pragma unroll
    for (int j = 0; j < 4; ++j) {
      const long nrow = tileN + wn * 64 + j * 16 + l16;
#pragma unroll
      for (int i = 0; i < 4; ++i) {
        const int w = pack_fp8x4(acc[i][j][0], acc[i][j][1], acc[i][j][2],
                                 acc[i][j][3]);
        const long mcol = tileM + wm * 64 + i * 16 + lq * 4;
        *(int*)&Vt[nrow * (long)ROWS + mcol] = w;
      }
    }
  }
}

// ---------------------------------------------------------------------------
// LayerNorm (faithful buggy form): y = (x - mu/sqrt(var)) * g + b, ddof=1.
// One 256-thr block per 768-elem row. Optionally zeroes Lzero[row].
// ---------------------------------------------------------------------------
template <typename T>
__global__ __launch_bounds__(256) void ln_kernel(
    const T* __restrict__ in, const float* __restrict__ g,
    const float* __restrict__ beta, bf16* __restrict__ out,
    float* __restrict__ Lzero) {
  const long row = blockIdx.x;
  if (Lzero != nullptr && threadIdx.x == 0) Lzero[row] = 0.f;
  const T* xr = in + row * DDIM;
  const int t = threadIdx.x;
  float v0 = to_f(xr[t]), v1 = to_f(xr[t + 256]), v2 = to_f(xr[t + 512]);
  float s = v0 + v1 + v2;
  float q = v0 * v0 + v1 * v1 + v2 * v2;
#pragma unroll
  for (int o = 32; o; o >>= 1) {
    s += __shfl_down(s, o);
    q += __shfl_down(q, o);
  }
  __shared__ float sb[4], qb[4];
  if ((t & 63) == 0) { sb[t >> 6] = s; qb[t >> 6] = q; }
  __syncthreads();
  const float S = sb[0] + sb[1] + sb[2] + sb[3];
  const float Q = qb[0] + qb[1] + qb[2] + qb[3];
  const float mu  = S * (1.0f / 768.0f);
  const float var = (Q - 768.0f * mu * mu) * (1.0f / 767.0f);
  const float sub = mu / sqrtf(var);
  bf16* orow = out + row * DDIM;
  orow[t]       = __float2bfloat16((v0 - sub) * g[t]       + beta[t]);
  orow[t + 256] = __float2bfloat16((v1 - sub) * g[t + 256] + beta[t + 256]);
  orow[t + 512] = __float2bfloat16((v2 - sub) * g[t + 512] + beta[t + 512]);
}

// ---------------------------------------------------------------------------
// Weight prep: z=0..2 transpose+cast wq/wk/wv; z=3..4 cast fc1/fc2.
// ---------------------------------------------------------------------------
__global__ void prep_weights(const float* __restrict__ wq,
                             const float* __restrict__ wk,
                             const float* __restrict__ wv,
                             const float* __restrict__ f1,
                             const float* __restrict__ f2,
                             bf16* wqt, bf16* wkt, bf16* wvt, bf16* f1b,
                             bf16* f2b) {
  __shared__ float tile[32][33];
  const float* src;
  bf16* dst;
  bool tr = true;
  switch (blockIdx.z) {
    case 0: src = wq; dst = wqt; break;
    case 1: src = wk; dst = wkt; break;
    case 2: src = wv; dst = wvt; break;
    case 3: src = f1; dst = f1b; tr = false; break;
    default: src = f2; dst = f2b; tr = false; break;
  }
  const int tx = threadIdx.x, ty = threadIdx.y;
  const int x = blockIdx.x * 32 + tx;
  const int y = blockIdx.y * 32 + ty;
  if (tr) {
#pragma unroll
    for (int r = 0; r < 4; ++r) tile[ty + 8 * r][tx] = src[(y + 8 * r) * DDIM + x];
    __syncthreads();
    const int ox = blockIdx.y * 32 + tx;
    const int oy = blockIdx.x * 32 + ty;
#pragma unroll
    for (int r = 0; r < 4; ++r)
      dst[(oy + 8 * r) * DDIM + ox] = __float2bfloat16(tile[tx][ty + 8 * r]);
  } else {
#pragma unroll
    for (int r = 0; r < 4; ++r)
      dst[(y + 8 * r) * DDIM + x] = __float2bfloat16(src[(y + 8 * r) * DDIM + x]);
  }
}

// ---------------------------------------------------------------------------
extern "C" void kernel_launch(void* const* d_in, const int* in_sizes, int n_in,
                              void* d_out, int out_size, void* d_ws,
                              size_t ws_size, hipStream_t stream) {
  const float* x     = (const float*)d_in[0];
  const float* ln1_g = (const float*)d_in[1];
  const float* ln1_b = (const float*)d_in[2];
  const float* wq    = (const float*)d_in[3];
  const float* wk    = (const float*)d_in[4];
  const float* wv    = (const float*)d_in[5];
  const float* ln2_g = (const float*)d_in[6];
  const float* ln2_b = (const float*)d_in[7];
  const float* f1w   = (const float*)d_in[8];
  const float* f1bias= (const float*)d_in[9];
  const float* f2w   = (const float*)d_in[10];
  const float* f2bias= (const float*)d_in[11];
  float* out = (float*)d_out;

  char* ws = (char*)d_ws;
  size_t off = 0;
  auto take = [&](size_t bytes) -> char* {
    char* p = ws + off;
    off += (bytes + 255) & ~(size_t)255;
    return p;
  };
  const size_t WB = (size_t)DDIM * DDIM * sizeof(bf16);
  const size_t MB = (size_t)ROWS * DDIM * sizeof(bf16);
  bf16* wqt = (bf16*)take(WB);
  bf16* wkt = (bf16*)take(WB);
  bf16* wvt = (bf16*)take(WB);
  bf16* f1b = (bf16*)take(WB);
  bf16* f2b = (bf16*)take(WB);
  float* Lsum = (float*)take((size_t)ROWS * sizeof(float));
  bf16* y1  = (bf16*)take(MB);
  bf16* Qm  = (bf16*)take(MB);
  bf16* Km  = (bf16*)take(MB);
  unsigned char* Vt8 = (unsigned char*)take((size_t)DDIM * ROWS);  // 12.6 MB
  unsigned char* Sb8 = (unsigned char*)take((size_t)NB * TT * TT); // 67 MB (P)
  // buffer reuse (strictly sequential stream):
  bf16* O  = y1;  // attention output (y1 dead after QKV)
  bf16* y2 = Qm;  // LN2 output      (Q dead after QK^T)
  bf16* h  = Km;  // MLP hidden      (K dead after QK^T)

  prep_weights<<<dim3(24, 24, 5), dim3(32, 8), 0, stream>>>(
      wq, wk, wv, f1w, f2w, wqt, wkt, wvt, f1b, f2b);

  // LN1 also zeroes Lsum (ws is re-poisoned before every timed call)
  ln_kernel<float><<<ROWS, 256, 0, stream>>>(x, ln1_g, ln1_b, y1, Lsum);

  // Fused QKV projections (M=16384, N=768, K=768); z=2 emits fp8 V^T
  gemm_qkv<<<dim3(6, 128, 3), 256, 0, stream>>>(y1, wqt, wkt, wvt, Qm, Km, Vt8);

  const float scale = 0.03608439182435161f;  // 1/sqrt(768)
  // S^T tiles (A=K, B=Q) -> P = exp(scale*S) fp8 row-major + row sums.
  gemm_bt<5, 32, 32><<<dim3(32 * 32 * NB), 256, 0, stream>>>(
      Km, DDIM, (long)TT * DDIM, Qm, DDIM, (long)TT * DDIM, Sb8, TT,
      (long)TT * TT, DDIM, scale, nullptr, nullptr, Lsum);

  // O = (P V) / Lsum, fp8 x fp8 MFMA
  gemm_pv<<<dim3(6 * 32 * NB), 256, 0, stream>>>(Sb8, Vt8, O, Lsum);

  ln_kernel<bf16><<<ROWS, 256, 0, stream>>>(O, ln2_g, ln2_b, y2, nullptr);

  // MLP
  gemm_bt<3, 0, 0><<<dim3(6, 128, 1), 256, 0, stream>>>(
      y2, DDIM, 0, f1b, DDIM, 0, h, DDIM, 0, DDIM, 1.f, f1bias, nullptr,
      nullptr);
  gemm_bt<4, 0, 0><<<dim3(6, 128, 1), 256, 0, stream>>>(
      h, DDIM, 0, f2b, DDIM, 0, out, DDIM, 0, DDIM, 1.f, f2bias, x, nullptr);
}